// Round 1
// baseline (6729.658 us; speedup 1.0000x reference)
//
#include <hip/hip_runtime.h>

// Problem dims
#define B_   2048
#define D_   256
#define K_   20
#define UD_  512
#define E_   64
#define H_   256
#define HID_ 512

typedef __attribute__((ext_vector_type(8))) short bf8;    // 8 x bf16 (4 VGPRs) MFMA A/B frag
typedef __attribute__((ext_vector_type(4))) float f32x4;  // MFMA C/D frag
typedef __attribute__((ext_vector_type(4))) float f4;

#define MFMA16(a,b,c) __builtin_amdgcn_mfma_f32_16x16x32_bf16(a, b, c, 0, 0, 0)

__device__ __forceinline__ unsigned short f2bf(float x) {
  unsigned u = __float_as_uint(x);
  u += 0x7fffu + ((u >> 16) & 1u);   // RNE
  return (unsigned short)(u >> 16);
}
__device__ __forceinline__ float sigf(float x)   { return 1.0f / (1.0f + __expf(-x)); }
__device__ __forceinline__ float tanhf_(float x) { return 1.0f - 2.0f / (__expf(2.0f * x) + 1.0f); }

// ---------------------------------------------------------------------------
// Pack a [N,K] row-major f32 weight into MFMA B-fragment order (bf16):
// frag (nt,kt): lane l holds W[nt*16+(l&15)][kt*32+(l>>4)*8 + j], j=0..7,
// stored at dst[((nt*KTtot + kt0 + kt)*64 + l)*8]. n >= Nsrc -> 0 (padding).
// ---------------------------------------------------------------------------
__global__ __launch_bounds__(256) void pack_w(const float* __restrict__ W,
    unsigned short* __restrict__ dst, int NT, int KTsrc, int KTtot, int kt0,
    int ldw, int Nsrc)
{
  int idx = blockIdx.x * 256 + threadIdx.x;
  int total = NT * KTsrc * 64;
  if (idx >= total) return;
  int l  = idx & 63;
  int fk = idx >> 6;
  int kt = fk % KTsrc;
  int nt = fk / KTsrc;
  int n = nt * 16 + (l & 15);
  int k = kt * 32 + ((l >> 4) * 8);
  bf8 o;
#pragma unroll
  for (int j = 0; j < 8; ++j)
    o[j] = (n < Nsrc) ? (short)f2bf(W[(size_t)n * ldw + k + j]) : (short)0;
  *(bf8*)(dst + (((size_t)(nt * KTtot + kt0 + kt)) * 64 + l) * 8) = o;
}

// f32 -> bf16 row-major convert (8 elems / thread)
__global__ __launch_bounds__(256) void cvt_bf(const float* __restrict__ src,
    unsigned short* __restrict__ dst, int n8)
{
  int i = blockIdx.x * 256 + threadIdx.x;
  if (i >= n8) return;
  const f4* s = (const f4*)(src + (size_t)i * 8);
  f4 v0 = s[0], v1 = s[1];
  bf8 o;
#pragma unroll
  for (int j = 0; j < 4; ++j) { o[j] = (short)f2bf(v0[j]); o[4 + j] = (short)f2bf(v1[j]); }
  *(bf8*)(dst + (size_t)i * 8) = o;
}

// ---------------------------------------------------------------------------
// Generic C = A @ W^T + bias. A bf16 [*, lda] row-major (+aoff col offset),
// Bp fragment-packed (KT k-tiles), C f32 or bf16 at [row*ldc + coff + n].
// Block: 256 thr = 4 waves (2x2), block tile 64x64, wave tile 32x32.
// ---------------------------------------------------------------------------
template<bool OUTBF>
__global__ __launch_bounds__(256) void gemm_bt(
    const unsigned short* __restrict__ A, int lda, int aoff,
    const unsigned short* __restrict__ Bp, int KT,
    void* __restrict__ Cptr, int ldc, int coff,
    const float* __restrict__ bias)
{
  int tid = threadIdx.x;
  int l = tid & 63, w = tid >> 6;
  int wr = w >> 1, wc = w & 1;
  int r0 = blockIdx.y * 64 + wr * 32;
  int n0 = blockIdx.x * 64 + wc * 32;
  int lr = l & 15, lk = (l >> 4) * 8;
  f32x4 acc[2][2] = {};
  const unsigned short* a0p = A + (size_t)(r0 + lr) * lda + aoff + lk;
  const unsigned short* a1p = A + (size_t)(r0 + 16 + lr) * lda + aoff + lk;
  int ntb = n0 >> 4;
  for (int kt = 0; kt < KT; ++kt) {
    bf8 a0 = *(const bf8*)(a0p + kt * 32);
    bf8 a1 = *(const bf8*)(a1p + kt * 32);
    bf8 b0 = *(const bf8*)(Bp + (((size_t)(ntb + 0) * KT + kt) * 64 + l) * 8);
    bf8 b1 = *(const bf8*)(Bp + (((size_t)(ntb + 1) * KT + kt) * 64 + l) * 8);
    acc[0][0] = MFMA16(a0, b0, acc[0][0]);
    acc[0][1] = MFMA16(a0, b1, acc[0][1]);
    acc[1][0] = MFMA16(a1, b0, acc[1][0]);
    acc[1][1] = MFMA16(a1, b1, acc[1][1]);
  }
#pragma unroll
  for (int mi = 0; mi < 2; ++mi)
#pragma unroll
  for (int nj = 0; nj < 2; ++nj)
#pragma unroll
  for (int r = 0; r < 4; ++r) {
    int row = r0 + mi * 16 + (l >> 4) * 4 + r;
    int n = n0 + nj * 16 + lr;
    float v = acc[mi][nj][r] + bias[n];
    if (OUTBF) ((unsigned short*)Cptr)[(size_t)row * ldc + coff + n] = f2bf(v);
    else       ((float*)Cptr)[(size_t)row * ldc + coff + n] = v;
  }
}

// LayerNorm(512) + SiLU over Hgb [2048,1024] (cols 0:512 gamma-branch, 512: beta).
// One wave per (row, branch).
__global__ __launch_bounds__(256) void ln_silu(
    const float* __restrict__ Hgb, unsigned short* __restrict__ Hsi,
    const float* __restrict__ gw, const float* __restrict__ gb,
    const float* __restrict__ bw, const float* __restrict__ bb)
{
  int tid = threadIdx.x;
  int l = tid & 63, w = tid >> 6;
  int gwv = blockIdx.x * 4 + w;
  int row = gwv >> 1, br = gwv & 1;
  const float* base = Hgb + (size_t)row * 1024 + br * 512 + l * 8;
  f4 v0 = *(const f4*)base;
  f4 v1 = *(const f4*)(base + 4);
  float s1 = 0.f, s2 = 0.f;
#pragma unroll
  for (int j = 0; j < 4; ++j) { s1 += v0[j] + v1[j]; s2 += v0[j] * v0[j] + v1[j] * v1[j]; }
  for (int m = 1; m < 64; m <<= 1) { s1 += __shfl_xor(s1, m, 64); s2 += __shfl_xor(s2, m, 64); }
  float mean = s1 * (1.0f / 512.0f);
  float var  = s2 * (1.0f / 512.0f) - mean * mean;
  float rstd = rsqrtf(var + 1e-5f);
  const float* W  = br ? bw : gw;
  const float* Bb = br ? bb : gb;
  bf8 o;
#pragma unroll
  for (int j = 0; j < 8; ++j) {
    float x = (j < 4) ? v0[j] : v1[j - 4];
    float y = (x - mean) * rstd * W[l * 8 + j] + Bb[l * 8 + j];
    o[j] = (short)f2bf(y * sigf(y));
  }
  *(bf8*)(Hsi + (size_t)row * 1024 + br * 512 + l * 8) = o;
}

// ---------------------------------------------------------------------------
// Step kernel A: layer-0 LSTM cell for step t (fused GEMM+cell), plus the
// log-softmax head for step t-1 in 32 extra blocks.
// gates0 = [xs_t | h0_{t-1}] @ [wih0;whh0]^T + b.  Block tile: 64 rows x 32
// h-cols (4 gate strips share the C-lane mapping -> lane-local cell update).
// ---------------------------------------------------------------------------
__global__ __launch_bounds__(256) void kA(
    int t,
    const unsigned short* __restrict__ H0r, unsigned short* __restrict__ H0w,
    const unsigned short* __restrict__ H1r,
    float* __restrict__ C0,
    const unsigned short* __restrict__ W0p,
    const unsigned short* __restrict__ E0,
    const float* __restrict__ GamBet,
    const int* __restrict__ X,
    const float* __restrict__ emb,
    const float* __restrict__ bih0, const float* __restrict__ bhh0,
    const unsigned short* __restrict__ Whp, const float* __restrict__ headb,
    float* __restrict__ logq)
{
  int tid = threadIdx.x;
  int l = tid & 63, w = tid >> 6;
  int lr = l & 15, lk = (l >> 4) * 8;
  int bx = blockIdx.x;
  if (bx < 256) {
    int rowtile = bx >> 3, coltile = bx & 7;
    int wr = w >> 1, wc = w & 1;
    int r0 = rowtile * 64 + wr * 32;
    int c0 = coltile * 32 + wc * 16;
    int rowA0 = r0 + lr, rowA1 = r0 + 16 + lr;
    f32x4 acc[2][4] = {};
    // xs fragments for the first 2 k-tiles (k 0..63)
    bf8 xa0[2], xa1[2];
    if (t == 0) {
#pragma unroll
      for (int kt = 0; kt < 2; ++kt) {
        xa0[kt] = *(const bf8*)(E0 + (size_t)rowA0 * E_ + kt * 32 + lk);
        xa1[kt] = *(const bf8*)(E0 + (size_t)rowA1 * E_ + kt * 32 + lk);
      }
    } else {
      int tok0 = X[rowA0 * D_ + t - 1];
      int tok1 = X[rowA1 * D_ + t - 1];
#pragma unroll
      for (int kt = 0; kt < 2; ++kt) {
        int k0 = kt * 32 + lk;
        const f4* e0p = (const f4*)(emb + tok0 * E_ + k0);
        const f4* e1p = (const f4*)(emb + tok1 * E_ + k0);
        const f4* g0p = (const f4*)(GamBet + (size_t)rowA0 * 128 + k0);
        const f4* g1p = (const f4*)(GamBet + (size_t)rowA1 * 128 + k0);
        const f4* b0p = (const f4*)(GamBet + (size_t)rowA0 * 128 + 64 + k0);
        const f4* b1p = (const f4*)(GamBet + (size_t)rowA1 * 128 + 64 + k0);
        bf8 oa, ob;
#pragma unroll
        for (int q = 0; q < 2; ++q) {
          f4 ev = e0p[q], gv = g0p[q], bv = b0p[q];
#pragma unroll
          for (int j = 0; j < 4; ++j) oa[q * 4 + j] = (short)f2bf(ev[j] * (1.0f + gv[j]) + bv[j]);
          ev = e1p[q]; gv = g1p[q]; bv = b1p[q];
#pragma unroll
          for (int j = 0; j < 4; ++j) ob[q * 4 + j] = (short)f2bf(ev[j] * (1.0f + gv[j]) + bv[j]);
        }
        xa0[kt] = oa; xa1[kt] = ob;
      }
    }
    int ntc = c0 >> 4;
#pragma unroll
    for (int kt = 0; kt < 10; ++kt) {
      bf8 a0, a1;
      if (kt < 2) { a0 = xa0[kt]; a1 = xa1[kt]; }
      else {
        a0 = *(const bf8*)(H0r + (size_t)rowA0 * H_ + (kt - 2) * 32 + lk);
        a1 = *(const bf8*)(H0r + (size_t)rowA1 * H_ + (kt - 2) * 32 + lk);
      }
#pragma unroll
      for (int g = 0; g < 4; ++g) {
        bf8 b = *(const bf8*)(W0p + (((size_t)(g * 16 + ntc) * 10 + kt) * 64 + l) * 8);
        acc[0][g] = MFMA16(a0, b, acc[0][g]);
        acc[1][g] = MFMA16(a1, b, acc[1][g]);
      }
    }
    int c = c0 + lr;
    float bi  = bih0[c]          + bhh0[c];
    float bff = bih0[H_ + c]     + bhh0[H_ + c];
    float bg  = bih0[2 * H_ + c] + bhh0[2 * H_ + c];
    float bo  = bih0[3 * H_ + c] + bhh0[3 * H_ + c];
#pragma unroll
    for (int mi = 0; mi < 2; ++mi)
#pragma unroll
    for (int r = 0; r < 4; ++r) {
      int row = r0 + mi * 16 + (l >> 4) * 4 + r;
      float iv = sigf(acc[mi][0][r] + bi);
      float fv = sigf(acc[mi][1][r] + bff);
      float gv = tanhf_(acc[mi][2][r] + bg);
      float ov = sigf(acc[mi][3][r] + bo);
      float cold = C0[(size_t)row * H_ + c];
      float cnew = fv * cold + iv * gv;
      C0[(size_t)row * H_ + c] = cnew;
      H0w[(size_t)row * H_ + c] = f2bf(ov * tanhf_(cnew));
    }
  } else {
    // ---- head for step t-1: logits = h1(t-1) @ head_w^T + head_b ----
    if (t == 0) return;
    int hb = bx - 256;
    int r0w = hb * 64 + w * 16;
    f32x4 acc0 = {}, acc1 = {};
    int rowA = r0w + lr;
#pragma unroll
    for (int kt = 0; kt < 8; ++kt) {
      bf8 a  = *(const bf8*)(H1r + (size_t)rowA * H_ + kt * 32 + lk);
      bf8 b0 = *(const bf8*)(Whp + (((size_t)(0 * 8 + kt)) * 64 + l) * 8);
      bf8 b1 = *(const bf8*)(Whp + (((size_t)(1 * 8 + kt)) * 64 + l) * 8);
      acc0 = MFMA16(a, b0, acc0);
      acc1 = MFMA16(a, b1, acc1);
    }
    float hb0 = headb[lr];
    float hb1 = (lr < 4) ? headb[16 + lr] : 0.f;
#pragma unroll
    for (int r = 0; r < 4; ++r) {
      int row = r0w + (l >> 4) * 4 + r;
      float v0 = acc0[r] + hb0;
      float v1 = (lr < 4) ? (acc1[r] + hb1) : -1e30f;
      float m = fmaxf(v0, v1);
#pragma unroll
      for (int msk = 1; msk < 16; msk <<= 1) m = fmaxf(m, __shfl_xor(m, msk, 64));
      float s = __expf(v0 - m) + ((lr < 4) ? __expf(v1 - m) : 0.f);
#pragma unroll
      for (int msk = 1; msk < 16; msk <<= 1) s += __shfl_xor(s, msk, 64);
      float lse = m + __logf(s);
      int tok = X[row * D_ + t - 1];
      float lt = ((lr == tok) ? v0 : 0.f) + ((lr + 16 == tok) ? v1 : 0.f);
#pragma unroll
      for (int msk = 1; msk < 16; msk <<= 1) lt += __shfl_xor(lt, msk, 64);
      if (lr == 0) logq[row] += lt - lse;
    }
  }
}

// Step kernel B: layer-1 LSTM cell: gates1 = [h0_t | h1_{t-1}] @ [wih1;whh1]^T + b.
__global__ __launch_bounds__(256) void kB(
    const unsigned short* __restrict__ H0c,
    const unsigned short* __restrict__ H1r,
    unsigned short* __restrict__ H1w,
    float* __restrict__ C1,
    const unsigned short* __restrict__ W1p,
    const float* __restrict__ bih1, const float* __restrict__ bhh1)
{
  int tid = threadIdx.x;
  int l = tid & 63, w = tid >> 6;
  int lr = l & 15, lk = (l >> 4) * 8;
  int bx = blockIdx.x;
  int rowtile = bx >> 3, coltile = bx & 7;
  int wr = w >> 1, wc = w & 1;
  int r0 = rowtile * 64 + wr * 32;
  int c0 = coltile * 32 + wc * 16;
  int rowA0 = r0 + lr, rowA1 = r0 + 16 + lr;
  int ntc = c0 >> 4;
  f32x4 acc[2][4] = {};
#pragma unroll
  for (int kt = 0; kt < 16; ++kt) {
    const unsigned short* s0;
    const unsigned short* s1;
    if (kt < 8) { s0 = H0c + (size_t)rowA0 * H_ + kt * 32 + lk;       s1 = H0c + (size_t)rowA1 * H_ + kt * 32 + lk; }
    else        { s0 = H1r + (size_t)rowA0 * H_ + (kt - 8) * 32 + lk; s1 = H1r + (size_t)rowA1 * H_ + (kt - 8) * 32 + lk; }
    bf8 a0 = *(const bf8*)s0;
    bf8 a1 = *(const bf8*)s1;
#pragma unroll
    for (int g = 0; g < 4; ++g) {
      bf8 b = *(const bf8*)(W1p + (((size_t)(g * 16 + ntc) * 16 + kt) * 64 + l) * 8);
      acc[0][g] = MFMA16(a0, b, acc[0][g]);
      acc[1][g] = MFMA16(a1, b, acc[1][g]);
    }
  }
  int c = c0 + lr;
  float bi  = bih1[c]          + bhh1[c];
  float bff = bih1[H_ + c]     + bhh1[H_ + c];
  float bg  = bih1[2 * H_ + c] + bhh1[2 * H_ + c];
  float bo  = bih1[3 * H_ + c] + bhh1[3 * H_ + c];
#pragma unroll
  for (int mi = 0; mi < 2; ++mi)
#pragma unroll
  for (int r = 0; r < 4; ++r) {
    int row = r0 + mi * 16 + (l >> 4) * 4 + r;
    float iv = sigf(acc[mi][0][r] + bi);
    float fv = sigf(acc[mi][1][r] + bff);
    float gv = tanhf_(acc[mi][2][r] + bg);
    float ov = sigf(acc[mi][3][r] + bo);
    float cold = C1[(size_t)row * H_ + c];
    float cnew = fv * cold + iv * gv;
    C1[(size_t)row * H_ + c] = cnew;
    H1w[(size_t)row * H_ + c] = f2bf(ov * tanhf_(cnew));
  }
}

// Final head (step 255) + write output.
__global__ __launch_bounds__(256) void k_final(
    const unsigned short* __restrict__ H1r,
    const unsigned short* __restrict__ Whp, const float* __restrict__ headb,
    const int* __restrict__ X, const float* __restrict__ logq,
    float* __restrict__ out)
{
  int tid = threadIdx.x;
  int l = tid & 63, w = tid >> 6;
  int lr = l & 15, lk = (l >> 4) * 8;
  int r0w = blockIdx.x * 64 + w * 16;
  f32x4 acc0 = {}, acc1 = {};
  int rowA = r0w + lr;
#pragma unroll
  for (int kt = 0; kt < 8; ++kt) {
    bf8 a  = *(const bf8*)(H1r + (size_t)rowA * H_ + kt * 32 + lk);
    bf8 b0 = *(const bf8*)(Whp + (((size_t)(0 * 8 + kt)) * 64 + l) * 8);
    bf8 b1 = *(const bf8*)(Whp + (((size_t)(1 * 8 + kt)) * 64 + l) * 8);
    acc0 = MFMA16(a, b0, acc0);
    acc1 = MFMA16(a, b1, acc1);
  }
  float hb0 = headb[lr];
  float hb1 = (lr < 4) ? headb[16 + lr] : 0.f;
#pragma unroll
  for (int r = 0; r < 4; ++r) {
    int row = r0w + (l >> 4) * 4 + r;
    float v0 = acc0[r] + hb0;
    float v1 = (lr < 4) ? (acc1[r] + hb1) : -1e30f;
    float m = fmaxf(v0, v1);
#pragma unroll
    for (int msk = 1; msk < 16; msk <<= 1) m = fmaxf(m, __shfl_xor(m, msk, 64));
    float s = __expf(v0 - m) + ((lr < 4) ? __expf(v1 - m) : 0.f);
#pragma unroll
    for (int msk = 1; msk < 16; msk <<= 1) s += __shfl_xor(s, msk, 64);
    float lse = m + __logf(s);
    int tok = X[row * D_ + 255];
    float lt = ((lr == tok) ? v0 : 0.f) + ((lr + 16 == tok) ? v1 : 0.f);
#pragma unroll
    for (int msk = 1; msk < 16; msk <<= 1) lt += __shfl_xor(lt, msk, 64);
    if (lr == 0) out[row] = logq[row] + (lt - lse);
  }
}

// ---------------------------------------------------------------------------
extern "C" void kernel_launch(void* const* d_in, const int* in_sizes, int n_in,
                              void* d_out, int out_size, void* d_ws, size_t ws_size,
                              hipStream_t stream)
{
  (void)in_sizes; (void)n_in; (void)out_size; (void)ws_size;
  const float* U    = (const float*)d_in[0];
  const int*   X    = (const int*)  d_in[1];
  const float* emb  = (const float*)d_in[2];
  const float* u0w  = (const float*)d_in[3];
  const float* u0b  = (const float*)d_in[4];
  const float* gw1  = (const float*)d_in[5];
  const float* gb1  = (const float*)d_in[6];
  const float* glnw = (const float*)d_in[7];
  const float* glnb = (const float*)d_in[8];
  const float* gw2  = (const float*)d_in[9];
  const float* gb2  = (const float*)d_in[10];
  const float* bw1  = (const float*)d_in[11];
  const float* bb1  = (const float*)d_in[12];
  const float* blnw = (const float*)d_in[13];
  const float* blnb = (const float*)d_in[14];
  const float* bw2  = (const float*)d_in[15];
  const float* bb2  = (const float*)d_in[16];
  const float* wih0 = (const float*)d_in[17];
  const float* whh0 = (const float*)d_in[18];
  const float* bih0 = (const float*)d_in[19];
  const float* bhh0 = (const float*)d_in[20];
  const float* wih1 = (const float*)d_in[21];
  const float* whh1 = (const float*)d_in[22];
  const float* bih1 = (const float*)d_in[23];
  const float* bhh1 = (const float*)d_in[24];
  const float* headw = (const float*)d_in[25];
  const float* headb = (const float*)d_in[26];
  float* out = (float*)d_out;

  char* ws = (char*)d_ws;
  size_t off = 0;
  auto alloc = [&](size_t bytes) -> void* {
    void* p = ws + off; off += (bytes + 255) & ~(size_t)255; return p;
  };
  unsigned short* W0p  = (unsigned short*)alloc((size_t)1024 * 320 * 2);
  unsigned short* W1p  = (unsigned short*)alloc((size_t)1024 * 512 * 2);
  unsigned short* Wg1p = (unsigned short*)alloc((size_t)512 * 512 * 2);
  unsigned short* Wb1p = (unsigned short*)alloc((size_t)512 * 512 * 2);
  unsigned short* Wg2p = (unsigned short*)alloc((size_t)64 * 512 * 2);
  unsigned short* Wb2p = (unsigned short*)alloc((size_t)64 * 512 * 2);
  unsigned short* Wu0p = (unsigned short*)alloc((size_t)64 * 512 * 2);
  unsigned short* Whp  = (unsigned short*)alloc((size_t)32 * 256 * 2);
  unsigned short* Ubf  = (unsigned short*)alloc((size_t)B_ * UD_ * 2);
  float*          Hgb  = (float*)alloc((size_t)B_ * 1024 * 4);
  unsigned short* Hsi  = (unsigned short*)alloc((size_t)B_ * 1024 * 2);
  float*          GamBet = (float*)alloc((size_t)B_ * 128 * 4);
  unsigned short* E0   = (unsigned short*)alloc((size_t)B_ * E_ * 2);
  size_t zoff = off;
  unsigned short* H0   = (unsigned short*)alloc((size_t)2 * B_ * H_ * 2);
  unsigned short* H1   = (unsigned short*)alloc((size_t)2 * B_ * H_ * 2);
  float*          C0   = (float*)alloc((size_t)B_ * H_ * 4);
  float*          C1   = (float*)alloc((size_t)B_ * H_ * 4);
  float*          logq = (float*)alloc((size_t)B_ * 4);
  size_t zbytes = off - zoff;

  hipMemsetAsync(ws + zoff, 0, zbytes, stream);

  auto pg = [](int tot) { return dim3((tot + 255) / 256); };
  // weight packs:                        W      dst   NT  KTs KTt kt0 ldw Nsrc
  pack_w<<<pg(64 * 2 * 64),  256, 0, stream>>>(wih0, W0p,  64,  2, 10, 0,  64, 1024);
  pack_w<<<pg(64 * 8 * 64),  256, 0, stream>>>(whh0, W0p,  64,  8, 10, 2, 256, 1024);
  pack_w<<<pg(64 * 8 * 64),  256, 0, stream>>>(wih1, W1p,  64,  8, 16, 0, 256, 1024);
  pack_w<<<pg(64 * 8 * 64),  256, 0, stream>>>(whh1, W1p,  64,  8, 16, 8, 256, 1024);
  pack_w<<<pg(32 * 16 * 64), 256, 0, stream>>>(gw1,  Wg1p, 32, 16, 16, 0, 512, 512);
  pack_w<<<pg(32 * 16 * 64), 256, 0, stream>>>(bw1,  Wb1p, 32, 16, 16, 0, 512, 512);
  pack_w<<<pg(4 * 16 * 64),  256, 0, stream>>>(gw2,  Wg2p,  4, 16, 16, 0, 512, 64);
  pack_w<<<pg(4 * 16 * 64),  256, 0, stream>>>(bw2,  Wb2p,  4, 16, 16, 0, 512, 64);
  pack_w<<<pg(4 * 16 * 64),  256, 0, stream>>>(u0w,  Wu0p,  4, 16, 16, 0, 512, 64);
  pack_w<<<pg(2 * 8 * 64),   256, 0, stream>>>(headw, Whp,  2,  8,  8, 0, 256, 20);
  cvt_bf<<<pg(B_ * UD_ / 8), 256, 0, stream>>>(U, Ubf, B_ * UD_ / 8);

  // FiLM branch hidden layers: Hgb[:,0:512]=U@gw1^T+gb1, [:,512:]=U@bw1^T+bb1
  gemm_bt<false><<<dim3(8, 32), 256, 0, stream>>>(Ubf, UD_, 0, Wg1p, 16, Hgb, 1024, 0,   gb1);
  gemm_bt<false><<<dim3(8, 32), 256, 0, stream>>>(Ubf, UD_, 0, Wb1p, 16, Hgb, 1024, 512, bb1);
  ln_silu<<<1024, 256, 0, stream>>>(Hgb, Hsi, glnw, glnb, blnw, blnb);
  // gam / bet -> GamBet [2048,128]
  gemm_bt<false><<<dim3(1, 32), 256, 0, stream>>>(Hsi, 1024, 0,   Wg2p, 16, GamBet, 128, 0,  gb2);
  gemm_bt<false><<<dim3(1, 32), 256, 0, stream>>>(Hsi, 1024, 512, Wb2p, 16, GamBet, 128, 64, bb2);
  // e0 -> E0 bf16
  gemm_bt<true><<<dim3(1, 32), 256, 0, stream>>>(Ubf, UD_, 0, Wu0p, 16, E0, E_, 0, u0b);

  const size_t HN = (size_t)B_ * H_;
  for (int t = 0; t < D_; ++t) {
    const unsigned short* h0r = H0 + ((t + 1) & 1) * HN;
    unsigned short*       h0w = H0 + (t & 1) * HN;
    const unsigned short* h1r = H1 + ((t + 1) & 1) * HN;   // h1(t-1)
    unsigned short*       h1w = H1 + (t & 1) * HN;
    kA<<<288, 256, 0, stream>>>(t, h0r, h0w, h1r, C0, W0p, E0, GamBet, X, emb,
                                bih0, bhh0, Whp, headb, logq);
    kB<<<256, 256, 0, stream>>>(h0w, h1r, h1w, C1, W1p, bih1, bhh1);
  }
  k_final<<<32, 256, 0, stream>>>(H1 + 1 * HN, Whp, headb, X, logq, out);
}